// Round 16
// baseline (117.502 us; speedup 1.0000x reference)
//
#include <hip/hip_runtime.h>
#include <hip/hip_bf16.h>
#include <stdint.h>

typedef unsigned short u16;
typedef __attribute__((ext_vector_type(8))) short bf16x8;
typedef __attribute__((ext_vector_type(4))) float f32x4;
typedef __attribute__((ext_vector_type(4))) unsigned int u32x4;
typedef const __attribute__((address_space(1))) unsigned int gu32;
typedef __attribute__((address_space(3))) unsigned int lu32;

#define B_    4
#define NH_   8
#define BH_   32
#define DH_   64
#define DIM_  512
#define NTOK  4352
#define NREAL 4351
#define TEXT_ 256
#define IMG_  64
#define MTOT  (B_*NTOK)   // 17408
#define PSTR  140         // Ps row stride (u16): 280B -> bank-advance 6 -> conflict-free b128

// q pre-scale: DH^-0.5 * log2(e), so softmax uses exp2 directly
#define QSCALE 0.18033688011112042f

static __device__ __forceinline__ u16 f2bf(float f){
  unsigned int x = __float_as_uint(f);
  x += 0x7fffu + ((x>>16)&1u);
  return (u16)(x>>16);
}

// ======== K0: fused prep — x->bf16 padded; LDS-tiled coalesced weight transposes ========
// blocks [0,8704): convert x; [8704,8896): w_qkv 64x64 tiles (8x24); [8896,8960): w_out (8x8)
__global__ __launch_bounds__(256) void k_prep(const float* __restrict__ x, u16* __restrict__ xp,
                                              const float* __restrict__ w_qkv, u16* __restrict__ wqT,
                                              const float* __restrict__ w_out, u16* __restrict__ woT){
  __shared__ u16 tile[64*68];
  const int blk = blockIdx.x;
  const int tid = threadIdx.x;
  if (blk < 8704){
    size_t u = (size_t)blk*256 + tid;
    size_t m = u >> 7;
    int cc = (int)(u & 127);
    int b = (int)(m / NTOK);
    int t = (int)(m % NTOK);
    unsigned int o0, o1;
    if (t == NREAL){ o0 = 0u; o1 = 0u; }
    else {
      const float4 v = *reinterpret_cast<const float4*>(x + ((size_t)b*NREAL + t)*DIM_ + cc*4);
      o0 = (unsigned)f2bf(v.x) | ((unsigned)f2bf(v.y)<<16);
      o1 = (unsigned)f2bf(v.z) | ((unsigned)f2bf(v.w)<<16);
    }
    unsigned int* dst = reinterpret_cast<unsigned int*>(xp + m*DIM_ + cc*4);
    dst[0] = o0; dst[1] = o1;
    return;
  }
  // ---- weight transpose tiles: fp32 [512][C] -> bf16 [C][512] ----
  int ti = blk - 8704;
  const float* src; u16* dst; int C, r0, c0;
  if (ti < 192){ src = w_qkv; dst = wqT; C = 1536; r0 = (ti & 7)*64; c0 = (ti >> 3)*64; }
  else { ti -= 192; src = w_out; dst = woT; C = 512;  r0 = (ti & 7)*64; c0 = (ti >> 3)*64; }
  // read: coalesced float4 rows -> bf16 tile
  #pragma unroll
  for (int it = 0; it < 4; ++it){
    const int rr  = it*16 + (tid >> 4);
    const int ccq = (tid & 15)*4;
    const float4 v = *reinterpret_cast<const float4*>(src + (size_t)(r0+rr)*C + c0 + ccq);
    u16 p[4] = { f2bf(v.x), f2bf(v.y), f2bf(v.z), f2bf(v.w) };
    *reinterpret_cast<uint2*>(&tile[rr*68 + ccq]) = *reinterpret_cast<const uint2*>(p);
  }
  __syncthreads();
  // write: coalesced uint2 along r (output is [C][512], row stride 512)
  #pragma unroll
  for (int it = 0; it < 4; ++it){
    const int cc = it*16 + (tid >> 4);
    const int rq = (tid & 15)*4;
    u16 p[4] = { tile[(rq+0)*68 + cc], tile[(rq+1)*68 + cc],
                 tile[(rq+2)*68 + cc], tile[(rq+3)*68 + cc] };
    *reinterpret_cast<uint2*>(dst + (size_t)(c0+cc)*512 + r0 + rq) = *reinterpret_cast<const uint2*>(p);
  }
}

// ================= 128x128 GEMM core (m97 structure, bf16 both operands) =================
struct GemmAcc { f32x4 a[4][4]; };

static __device__ __forceinline__ void gemm128_core(const u16* __restrict__ A, const u16* __restrict__ Bt,
                                                    u16* As, u16* Bs, int m0, int c0, GemmAcc& G){
  const int tid  = threadIdx.x;
  const int lane = tid & 63;
  const int wave = tid >> 6;
  const int hi   = lane >> 4;
  const int sub  = lane >> 3;
  const int cc   = lane & 7;
  const int cg   = cc ^ sub;        // pre-swizzled global chunk

  const u16* ga = A  + (size_t)(m0 + wave*32 + sub)*DIM_ + cg*8;
  const u16* gb = Bt + (size_t)(c0 + wave*32 + sub)*DIM_ + cg*8;
  const int lds0 = (wave*32)*128;

  for (int k0 = 0; k0 < DIM_; k0 += 64){
    __syncthreads();
    #pragma unroll
    for (int i = 0; i < 4; ++i){
      __builtin_amdgcn_global_load_lds((gu32*)(ga + (size_t)i*8*DIM_), (lu32*)((char*)As + lds0 + i*8*128), 16, 0, 0);
      __builtin_amdgcn_global_load_lds((gu32*)(gb + (size_t)i*8*DIM_), (lu32*)((char*)Bs + lds0 + i*8*128), 16, 0, 0);
    }
    ga += 64; gb += 64;
    __syncthreads();

    bf16x8 af[4][2], bf[4][2];
    #pragma unroll
    for (int mi = 0; mi < 4; ++mi){
      const int r = (wave>>1)*64 + mi*16 + (lane & 15);
      #pragma unroll
      for (int ks = 0; ks < 2; ++ks){
        const int chunk = ks*4 + hi;
        af[mi][ks] = *reinterpret_cast<const bf16x8*>((const char*)As + r*128 + ((chunk*16) ^ ((r&7)<<4)));
      }
    }
    #pragma unroll
    for (int ni = 0; ni < 4; ++ni){
      const int r = (wave&1)*64 + ni*16 + (lane & 15);
      #pragma unroll
      for (int ks = 0; ks < 2; ++ks){
        const int chunk = ks*4 + hi;
        bf[ni][ks] = *reinterpret_cast<const bf16x8*>((const char*)Bs + r*128 + ((chunk*16) ^ ((r&7)<<4)));
      }
    }
    #pragma unroll
    for (int ks = 0; ks < 2; ++ks)
      #pragma unroll
      for (int mi = 0; mi < 4; ++mi)
        #pragma unroll
        for (int ni = 0; ni < 4; ++ni)
          G.a[mi][ni] = __builtin_amdgcn_mfma_f32_16x16x32_bf16(af[mi][ks], bf[ni][ks], G.a[mi][ni], 0,0,0);
  }
}

// qkv GEMM: q/k -> qk rows (q pre-scaled by QSCALE); v -> vT[bh][d][t] directly.
// Default block order (x-fastest) is L2-optimal: do NOT swizzle (R14 evidence).
__global__ __launch_bounds__(256) void k_gemm_qkv(const u16* __restrict__ A, const u16* __restrict__ Bt,
                                                  u16* __restrict__ qk, u16* __restrict__ vT){
  __shared__ u16 As[128*64];
  __shared__ u16 Bs[128*64];
  const int lane = threadIdx.x & 63;
  const int wave = threadIdx.x >> 6;
  const int hi   = lane >> 4;
  const int m0 = blockIdx.x * 128;
  const int c0 = blockIdx.y * 128;
  GemmAcc G = {};
  gemm128_core(A, Bt, As, Bs, m0, c0, G);

  const int which = c0 >> 9;        // block-uniform: 0=q 1=k 2=v
  if (which < 2){
    const float scl = (which == 0) ? QSCALE : 1.0f;
    #pragma unroll
    for (int mi = 0; mi < 4; ++mi){
      #pragma unroll
      for (int ni = 0; ni < 4; ++ni){
        #pragma unroll
        for (int reg = 0; reg < 4; ++reg){
          const int m   = m0 + (wave>>1)*64 + mi*16 + hi*4 + reg;
          const int col = c0 + (wave&1)*64 + ni*16 + (lane & 15);
          const int h = (col >> 6) & 7, d = col & 63;
          const int b = m / NTOK, t = m % NTOK;
          qk[((size_t)(which*BH_ + b*NH_ + h)*NTOK + t)*DH_ + d] = f2bf(G.a[mi][ni][reg] * scl);
        }
      }
    }
  } else {
    #pragma unroll
    for (int mi = 0; mi < 4; ++mi){
      #pragma unroll
      for (int ni = 0; ni < 4; ++ni){
        const int m = m0 + (wave>>1)*64 + mi*16 + hi*4;
        const int b = m / NTOK, t = m % NTOK;
        const int col = c0 + (wave&1)*64 + ni*16 + (lane & 15);
        const int h = (col >> 6) & 7, d = col & 63;
        uint2 o;
        o.x = (unsigned)f2bf(G.a[mi][ni][0]) | ((unsigned)f2bf(G.a[mi][ni][1]) << 16);
        o.y = (unsigned)f2bf(G.a[mi][ni][2]) | ((unsigned)f2bf(G.a[mi][ni][3]) << 16);
        *reinterpret_cast<uint2*>(vT + ((size_t)(b*NH_ + h)*DH_ + d)*NTOK + t) = o;
      }
    }
  }
}

__global__ __launch_bounds__(256) void k_gemm_out(const u16* __restrict__ A, const u16* __restrict__ Bt,
                                                  const float* __restrict__ bias, float* __restrict__ out){
  __shared__ u16 As[128*64];
  __shared__ u16 Bs[128*64];
  const int lane = threadIdx.x & 63;
  const int wave = threadIdx.x >> 6;
  const int m0 = blockIdx.x * 128;
  const int c0 = blockIdx.y * 128;
  GemmAcc G = {};
  gemm128_core(A, Bt, As, Bs, m0, c0, G);

  #pragma unroll
  for (int mi = 0; mi < 4; ++mi){
    #pragma unroll
    for (int ni = 0; ni < 4; ++ni){
      #pragma unroll
      for (int reg = 0; reg < 4; ++reg){
        const int m = m0 + (wave>>1)*64 + mi*16 + (lane>>4)*4 + reg;
        const int c = c0 + (wave&1)*64 + ni*16 + (lane & 15);
        const int b = m / NTOK, t = m % NTOK;
        if (t < NREAL)
          out[((size_t)b*NREAL + t)*DIM_ + c] = G.a[mi][ni][reg] + bias[c];
      }
    }
  }
}

// ---------------- fused MFMA attention core (R12 staging + O^T epilogue, PSTR=140) ----------------
template<int NT, bool IMG>
__device__ __forceinline__ void attn_core(const u16* __restrict__ qkv, const u16* __restrict__ vT,
                                          u16* __restrict__ att, u16* KVs, u16* PsAll,
                                          int bh, int yrow){
  constexpr int NCH = (NT + 7) / 8;
  constexpr int Y   = IMG ? 0 : (NT - 4) / 4;
  const int tid = threadIdx.x, lane = tid & 63, wave = tid >> 6, hi = lane >> 4;
  const int ktlim = (IMG ? TEXT_/16 : 4*Y) + wave;   // last tile this wave can touch
  const int q0 = IMG ? (TEXT_ + yrow*IMG_) : (Y*64);
  const u16* qpl = qkv + (size_t)bh*NTOK*DH_;
  const u16* kpl = qkv + (size_t)(BH_ + bh)*NTOK*DH_;
  const u16* vTp = vT  + (size_t)bh*DH_*NTOK;
  u16* Ps = PsAll + wave*(16*PSTR);

  bf16x8 qf[2];
  {
    const int qt = q0 + wave*16 + (lane & 15);
    qf[0] = *reinterpret_cast<const bf16x8*>(qpl + (size_t)qt*DH_ + hi*8);
    qf[1] = *reinterpret_cast<const bf16x8*>(qpl + (size_t)qt*DH_ + 32 + hi*8);
  }

  f32x4 sacc[NT] = {};

  // ---- QK^T ----
  #pragma unroll
  for (int c = 0; c < NCH; ++c){
    const int TC = (NT - c*8 < 8) ? (NT - c*8) : 8;
    __syncthreads();
    // async K stage: rows r = p*32 + wave*8 + sub (8 rows/instr), src chunk = cc^sub
    #pragma unroll
    for (int p = 0; p < 4; ++p){
      if (p < TC*16/32){
        const int r  = p*32 + (tid >> 3);
        const int j  = c*128 + r;
        const int krow = (!IMG || j < TEXT_) ? j : (TEXT_ + yrow*IMG_ + (j - TEXT_));
        const int cs = (lane & 7) ^ (lane >> 3);
        __builtin_amdgcn_global_load_lds((gu32*)(kpl + (size_t)krow*DH_ + cs*8),
            (lu32*)((char*)KVs + (p*32 + wave*8)*128), 16, 0, 0);
      }
    }
    __syncthreads();
    __builtin_amdgcn_s_setprio(1);
    #pragma unroll
    for (int kt2 = 0; kt2 < 8; ++kt2){
      if (kt2 < TC && (c*8 + kt2) <= ktlim){
        const int kt = c*8 + kt2;
        const int rr = kt2*16 + (lane & 15);
        bf16x8 b0 = *reinterpret_cast<const bf16x8*>((char*)KVs + rr*128 + (((0 + hi)*16) ^ ((rr&7)<<4)));
        bf16x8 b1 = *reinterpret_cast<const bf16x8*>((char*)KVs + rr*128 + (((4 + hi)*16) ^ ((rr&7)<<4)));
        sacc[kt] = __builtin_amdgcn_mfma_f32_16x16x32_bf16(qf[0], b0, sacc[kt], 0,0,0);
        sacc[kt] = __builtin_amdgcn_mfma_f32_16x16x32_bf16(qf[1], b1, sacc[kt], 0,0,0);
      }
    }
    __builtin_amdgcn_s_setprio(0);
  }

  // ---- causal mask (only tiles this wave computed) ----
  const int qb = wave*16 + hi*4;
  #pragma unroll
  for (int kt = 0; kt < NT; ++kt){
    if (kt <= ktlim && ((IMG && kt >= TEXT_/16) || (!IMG && kt*16 + 15 > Y*64))){
      #pragma unroll
      for (int reg = 0; reg < 4; ++reg){
        const int j = kt*16 + (lane & 15);
        const bool valid = IMG ? ((j - TEXT_) <= (qb + reg)) : (j <= Y*64 + qb + reg);
        if (!valid) sacc[kt][reg] = -1e30f;
      }
    }
  }

  // ---- exact softmax (exp2; skipped tiles stay 0 in sacc and excluded) ----
  float mr[4], inv[4];
  #pragma unroll
  for (int reg = 0; reg < 4; ++reg){
    float m = sacc[0][reg];
    #pragma unroll
    for (int kt = 1; kt < NT; ++kt) if (kt <= ktlim) m = fmaxf(m, sacc[kt][reg]);
    #pragma unroll
    for (int msk = 1; msk < 16; msk <<= 1) m = fmaxf(m, __shfl_xor(m, msk));
    mr[reg] = m;
  }
  #pragma unroll
  for (int reg = 0; reg < 4; ++reg){
    float l = 0.f;
    #pragma unroll
    for (int kt = 0; kt < NT; ++kt){
      if (kt <= ktlim){
        const float p = __builtin_amdgcn_exp2f(sacc[kt][reg] - mr[reg]);
        sacc[kt][reg] = p;
        l += p;
      }
    }
    #pragma unroll
    for (int msk = 1; msk < 16; msk <<= 1) l += __shfl_xor(l, msk);
    inv[reg] = 1.f / l;
  }

  // ---- PV (O^T via swapped operands) ----
  f32x4 oacc[4] = {};
  #pragma unroll
  for (int c = 0; c < NCH; ++c){
    const int TC = (NT - c*8 < 8) ? (NT - c*8) : 8;
    __syncthreads();
    if (TC == 8){
      // async V stage: 4 p-steps, rows dd = p*16 + wave*4 + hi (4 rows/instr),
      // src chunk = (lane&15) ^ (dd&7); all TC==8 chunks are text keys (j<256).
      #pragma unroll
      for (int p = 0; p < 4; ++p){
        const int dd = p*16 + wave*4 + (lane >> 4);
        const int ccs = (lane & 15) ^ (dd & 7);
        __builtin_amdgcn_global_load_lds((gu32*)(vTp + (size_t)dd*NTOK + c*128 + ccs*8),
            (lu32*)((char*)KVs + (p*16 + wave*4)*256), 16, 0, 0);
      }
    } else {
      // image / tail chunk: 64 keys per row, reg-staged (128B half-rows)
      #pragma unroll
      for (int p = 0; p < 2; ++p){
        const int idx = p*256 + tid;
        const int dd = idx >> 3;
        const int cc = idx & 7;
        const int j  = c*128 + cc*8;
        const int col = (!IMG || j < TEXT_) ? j : (TEXT_ + yrow*IMG_ + (j - TEXT_));
        u32x4 d = *reinterpret_cast<const u32x4*>(vTp + (size_t)dd*NTOK + col);
        *reinterpret_cast<u32x4*>((char*)KVs + dd*256 + ((cc*16) ^ ((dd&7)<<4))) = d;
      }
    }
    // write normalized P (bf16); skipped tiles have sacc==0 -> writes 0 (required:
    // Ps buffer is reused across chunks, so every slot must be refreshed)
    #pragma unroll
    for (int kt2 = 0; kt2 < 8; ++kt2){
      if (kt2 < TC){
        const int kt = c*8 + kt2;
        #pragma unroll
        for (int reg = 0; reg < 4; ++reg){
          const int q  = hi*4 + reg;
          const int kl = kt2*16 + (lane & 15);
          Ps[q*PSTR + kl] = f2bf(sacc[kt][reg] * inv[reg]);
        }
      }
    }
    __syncthreads();
    __builtin_amdgcn_s_setprio(1);
    #pragma unroll
    for (int kc = 0; kc < 4; ++kc){
      if (kc < TC/2 && (c*8 + kc*2) <= ktlim){
        bf16x8 pa = *reinterpret_cast<const bf16x8*>(&Ps[(lane & 15)*PSTR + kc*32 + hi*8]);
        #pragma unroll
        for (int ct = 0; ct < 4; ++ct){
          const int dd = ct*16 + (lane & 15);
          bf16x8 vb = *reinterpret_cast<const bf16x8*>((char*)KVs + dd*256 + (((kc*4 + hi)*16) ^ ((dd&7)<<4)));
          oacc[ct] = __builtin_amdgcn_mfma_f32_16x16x32_bf16(vb, pa, oacc[ct], 0,0,0);  // O^T
        }
      }
    }
    __builtin_amdgcn_s_setprio(0);
  }

  // ---- store O^T: lane owns q = lane&15; d = ct*16 + hi*4 + reg -> 8B stores ----
  const int b = bh >> 3, h = bh & 7;
  const int t = q0 + wave*16 + (lane & 15);
  u16* orow = att + ((size_t)b*NTOK + t)*DIM_ + h*DH_;
  #pragma unroll
  for (int ct = 0; ct < 4; ++ct){
    uint2 o;
    o.x = (unsigned)f2bf(oacc[ct][0]) | ((unsigned)f2bf(oacc[ct][1]) << 16);
    o.y = (unsigned)f2bf(oacc[ct][2]) | ((unsigned)f2bf(oacc[ct][3]) << 16);
    *reinterpret_cast<uint2*>(orow + ct*16 + hi*4) = o;
  }
}

// merged attention: y in [0,64) = image axial row y; y in [64,68) = text q-tile y-64
__global__ __launch_bounds__(256, 4) void k_attn(const u16* __restrict__ qkv, const u16* __restrict__ vT,
                                                 u16* __restrict__ att){
  __shared__ u16 KVs[128*64];
  __shared__ u16 Ps[4*16*PSTR];
  const int y = blockIdx.y;
  if (y < 64){
    attn_core<20, true>(qkv, vT, att, KVs, Ps, blockIdx.x, y);
  } else {
    switch (y - 64){
      case 0: attn_core< 4, false>(qkv, vT, att, KVs, Ps, blockIdx.x, 0); break;
      case 1: attn_core< 8, false>(qkv, vT, att, KVs, Ps, blockIdx.x, 0); break;
      case 2: attn_core<12, false>(qkv, vT, att, KVs, Ps, blockIdx.x, 0); break;
      default: attn_core<16, false>(qkv, vT, att, KVs, Ps, blockIdx.x, 0); break;
    }
  }
}

// ---------------- launch ----------------
extern "C" void kernel_launch(void* const* d_in, const int* in_sizes, int n_in,
                              void* d_out, int out_size, void* d_ws, size_t ws_size,
                              hipStream_t stream) {
  const float* x     = (const float*)d_in[0];
  const float* w_qkv = (const float*)d_in[2];
  const float* w_out = (const float*)d_in[3];
  const float* b_out = (const float*)d_in[4];
  float* out = (float*)d_out;

  char* ws = (char*)d_ws;
  u16* xp  = (u16*)(ws);                                        // 17,825,792 B
  u16* vT  = (u16*)(ws + 17825792);                             // 17,825,792 B
  u16* wqT = (u16*)(ws + 2*17825792);                           //  1,572,864 B
  u16* woT = (u16*)(ws + 2*17825792 + 1572864);                 //    524,288 B
  u16* qk  = (u16*)(ws + 2*17825792 + 1572864 + 524288);        // 35,651,584 B (q,k planes)
  u16* att = (u16*)(ws + 2*17825792 + 1572864 + 524288 + 35651584); // 17,825,792 B

  k_prep     <<<dim3(8960),    dim3(256), 0, stream>>>(x, xp, w_qkv, wqT, w_out, woT);
  k_gemm_qkv <<<dim3(136, 12), dim3(256), 0, stream>>>(xp, wqT, qk, vT);
  k_attn     <<<dim3(32, 68),  dim3(256), 0, stream>>>(qk, vT, att);
  k_gemm_out <<<dim3(136, 4),  dim3(256), 0, stream>>>(att, woT, b_out, out);
}

// Round 17
// 113.035 us; speedup vs baseline: 1.0395x; 1.0395x over previous
//
#include <hip/hip_runtime.h>
#include <hip/hip_bf16.h>
#include <stdint.h>

typedef unsigned short u16;
typedef __attribute__((ext_vector_type(8))) short bf16x8;
typedef __attribute__((ext_vector_type(4))) float f32x4;
typedef __attribute__((ext_vector_type(4))) unsigned int u32x4;
typedef const __attribute__((address_space(1))) unsigned int gu32;
typedef __attribute__((address_space(3))) unsigned int lu32;

#define B_    4
#define NH_   8
#define BH_   32
#define DH_   64
#define DIM_  512
#define NTOK  4352
#define NREAL 4351
#define TEXT_ 256
#define IMG_  64
#define MTOT  (B_*NTOK)   // 17408

// q pre-scale: DH^-0.5 * log2(e), so softmax uses exp2 directly
#define QSCALE 0.18033688011112042f

static __device__ __forceinline__ u16 f2bf(float f){
  unsigned int x = __float_as_uint(f);
  x += 0x7fffu + ((x>>16)&1u);
  return (u16)(x>>16);
}

// ======== K0: fused prep — x->bf16 padded, w_qkv^T, w_out^T (block-range dispatch) ========
__global__ __launch_bounds__(256) void k_prep(const float* __restrict__ x, u16* __restrict__ xp,
                                              const float* __restrict__ w_qkv, u16* __restrict__ wqT,
                                              const float* __restrict__ w_out, u16* __restrict__ woT){
  const int blk = blockIdx.x;
  if (blk < 8704){
    size_t u = (size_t)blk*256 + threadIdx.x;
    size_t m = u >> 7;
    int cc = (int)(u & 127);
    int b = (int)(m / NTOK);
    int t = (int)(m % NTOK);
    unsigned int o0, o1;
    if (t == NREAL){ o0 = 0u; o1 = 0u; }
    else {
      const float4 v = *reinterpret_cast<const float4*>(x + ((size_t)b*NREAL + t)*DIM_ + cc*4);
      o0 = (unsigned)f2bf(v.x) | ((unsigned)f2bf(v.y)<<16);
      o1 = (unsigned)f2bf(v.z) | ((unsigned)f2bf(v.w)<<16);
    }
    unsigned int* dst = reinterpret_cast<unsigned int*>(xp + m*DIM_ + cc*4);
    dst[0] = o0; dst[1] = o1;
  } else if (blk < 11776){
    size_t gid = (size_t)(blk - 8704)*256 + threadIdx.x;   // R=512, C=1536
    int c = (int)(gid >> 9);
    int r = (int)(gid & 511);
    wqT[gid] = f2bf(w_qkv[(size_t)r*1536 + c]);
  } else {
    size_t gid = (size_t)(blk - 11776)*256 + threadIdx.x;  // R=512, C=512
    int c = (int)(gid >> 9);
    int r = (int)(gid & 511);
    woT[gid] = f2bf(w_out[(size_t)r*512 + c]);
  }
}

// ================= 128x128 GEMM core (m97 structure, bf16 both operands) =================
struct GemmAcc { f32x4 a[4][4]; };

static __device__ __forceinline__ void gemm128_core(const u16* __restrict__ A, const u16* __restrict__ Bt,
                                                    u16* As, u16* Bs, int m0, int c0, GemmAcc& G){
  const int tid  = threadIdx.x;
  const int lane = tid & 63;
  const int wave = tid >> 6;
  const int hi   = lane >> 4;
  const int sub  = lane >> 3;
  const int cc   = lane & 7;
  const int cg   = cc ^ sub;        // pre-swizzled global chunk

  const u16* ga = A  + (size_t)(m0 + wave*32 + sub)*DIM_ + cg*8;
  const u16* gb = Bt + (size_t)(c0 + wave*32 + sub)*DIM_ + cg*8;
  const int lds0 = (wave*32)*128;

  for (int k0 = 0; k0 < DIM_; k0 += 64){
    __syncthreads();
    #pragma unroll
    for (int i = 0; i < 4; ++i){
      __builtin_amdgcn_global_load_lds((gu32*)(ga + (size_t)i*8*DIM_), (lu32*)((char*)As + lds0 + i*8*128), 16, 0, 0);
      __builtin_amdgcn_global_load_lds((gu32*)(gb + (size_t)i*8*DIM_), (lu32*)((char*)Bs + lds0 + i*8*128), 16, 0, 0);
    }
    ga += 64; gb += 64;
    __syncthreads();

    bf16x8 af[4][2], bf[4][2];
    #pragma unroll
    for (int mi = 0; mi < 4; ++mi){
      const int r = (wave>>1)*64 + mi*16 + (lane & 15);
      #pragma unroll
      for (int ks = 0; ks < 2; ++ks){
        const int chunk = ks*4 + hi;
        af[mi][ks] = *reinterpret_cast<const bf16x8*>((const char*)As + r*128 + ((chunk*16) ^ ((r&7)<<4)));
      }
    }
    #pragma unroll
    for (int ni = 0; ni < 4; ++ni){
      const int r = (wave&1)*64 + ni*16 + (lane & 15);
      #pragma unroll
      for (int ks = 0; ks < 2; ++ks){
        const int chunk = ks*4 + hi;
        bf[ni][ks] = *reinterpret_cast<const bf16x8*>((const char*)Bs + r*128 + ((chunk*16) ^ ((r&7)<<4)));
      }
    }
    #pragma unroll
    for (int ks = 0; ks < 2; ++ks)
      #pragma unroll
      for (int mi = 0; mi < 4; ++mi)
        #pragma unroll
        for (int ni = 0; ni < 4; ++ni)
          G.a[mi][ni] = __builtin_amdgcn_mfma_f32_16x16x32_bf16(af[mi][ks], bf[ni][ks], G.a[mi][ni], 0,0,0);
  }
}

// qkv GEMM: q/k -> qk rows (q pre-scaled by QSCALE); v -> vT[bh][d][t] directly.
// Default block order (x-fastest) is already L2-optimal: 136 consecutive blocks
// share one B-panel; each XCD gets ~17 contiguous m-tiles. Do NOT swizzle (R14).
__global__ __launch_bounds__(256) void k_gemm_qkv(const u16* __restrict__ A, const u16* __restrict__ Bt,
                                                  u16* __restrict__ qk, u16* __restrict__ vT){
  __shared__ u16 As[128*64];
  __shared__ u16 Bs[128*64];
  const int lane = threadIdx.x & 63;
  const int wave = threadIdx.x >> 6;
  const int hi   = lane >> 4;
  const int m0 = blockIdx.x * 128;
  const int c0 = blockIdx.y * 128;
  GemmAcc G = {};
  gemm128_core(A, Bt, As, Bs, m0, c0, G);

  const int which = c0 >> 9;        // block-uniform: 0=q 1=k 2=v
  if (which < 2){
    const float scl = (which == 0) ? QSCALE : 1.0f;
    #pragma unroll
    for (int mi = 0; mi < 4; ++mi){
      #pragma unroll
      for (int ni = 0; ni < 4; ++ni){
        #pragma unroll
        for (int reg = 0; reg < 4; ++reg){
          const int m   = m0 + (wave>>1)*64 + mi*16 + hi*4 + reg;
          const int col = c0 + (wave&1)*64 + ni*16 + (lane & 15);
          const int h = (col >> 6) & 7, d = col & 63;
          const int b = m / NTOK, t = m % NTOK;
          qk[((size_t)(which*BH_ + b*NH_ + h)*NTOK + t)*DH_ + d] = f2bf(G.a[mi][ni][reg] * scl);
        }
      }
    }
  } else {
    #pragma unroll
    for (int mi = 0; mi < 4; ++mi){
      #pragma unroll
      for (int ni = 0; ni < 4; ++ni){
        const int m = m0 + (wave>>1)*64 + mi*16 + hi*4;
        const int b = m / NTOK, t = m % NTOK;
        const int col = c0 + (wave&1)*64 + ni*16 + (lane & 15);
        const int h = (col >> 6) & 7, d = col & 63;
        uint2 o;
        o.x = (unsigned)f2bf(G.a[mi][ni][0]) | ((unsigned)f2bf(G.a[mi][ni][1]) << 16);
        o.y = (unsigned)f2bf(G.a[mi][ni][2]) | ((unsigned)f2bf(G.a[mi][ni][3]) << 16);
        *reinterpret_cast<uint2*>(vT + ((size_t)(b*NH_ + h)*DH_ + d)*NTOK + t) = o;
      }
    }
  }
}

__global__ __launch_bounds__(256) void k_gemm_out(const u16* __restrict__ A, const u16* __restrict__ Bt,
                                                  const float* __restrict__ bias, float* __restrict__ out){
  __shared__ u16 As[128*64];
  __shared__ u16 Bs[128*64];
  const int lane = threadIdx.x & 63;
  const int wave = threadIdx.x >> 6;
  const int m0 = blockIdx.x * 128;
  const int c0 = blockIdx.y * 128;
  GemmAcc G = {};
  gemm128_core(A, Bt, As, Bs, m0, c0, G);

  #pragma unroll
  for (int mi = 0; mi < 4; ++mi){
    #pragma unroll
    for (int ni = 0; ni < 4; ++ni){
      #pragma unroll
      for (int reg = 0; reg < 4; ++reg){
        const int m = m0 + (wave>>1)*64 + mi*16 + (lane>>4)*4 + reg;
        const int c = c0 + (wave&1)*64 + ni*16 + (lane & 15);
        const int b = m / NTOK, t = m % NTOK;
        if (t < NREAL)
          out[((size_t)b*NREAL + t)*DIM_ + c] = G.a[mi][ni][reg] + bias[c];
      }
    }
  }
}

// ---------------- fused MFMA attention core (R12 staging + O^T epilogue) ----------------
template<int NT, bool IMG>
__device__ __forceinline__ void attn_core(const u16* __restrict__ qkv, const u16* __restrict__ vT,
                                          u16* __restrict__ att, u16* KVs, u16* PsAll,
                                          int bh, int yrow){
  constexpr int NCH = (NT + 7) / 8;
  constexpr int Y   = IMG ? 0 : (NT - 4) / 4;
  const int tid = threadIdx.x, lane = tid & 63, wave = tid >> 6, hi = lane >> 4;
  const int ktlim = (IMG ? TEXT_/16 : 4*Y) + wave;   // last tile this wave can touch
  const int q0 = IMG ? (TEXT_ + yrow*IMG_) : (Y*64);
  const u16* qpl = qkv + (size_t)bh*NTOK*DH_;
  const u16* kpl = qkv + (size_t)(BH_ + bh)*NTOK*DH_;
  const u16* vTp = vT  + (size_t)bh*DH_*NTOK;
  u16* Ps = PsAll + wave*(16*136);

  bf16x8 qf[2];
  {
    const int qt = q0 + wave*16 + (lane & 15);
    qf[0] = *reinterpret_cast<const bf16x8*>(qpl + (size_t)qt*DH_ + hi*8);
    qf[1] = *reinterpret_cast<const bf16x8*>(qpl + (size_t)qt*DH_ + 32 + hi*8);
  }

  f32x4 sacc[NT] = {};

  // ---- QK^T ----
  #pragma unroll
  for (int c = 0; c < NCH; ++c){
    const int TC = (NT - c*8 < 8) ? (NT - c*8) : 8;
    __syncthreads();
    // async K stage: rows r = p*32 + wave*8 + sub (8 rows/instr), src chunk = cc^sub
    #pragma unroll
    for (int p = 0; p < 4; ++p){
      if (p < TC*16/32){
        const int r  = p*32 + (tid >> 3);
        const int j  = c*128 + r;
        const int krow = (!IMG || j < TEXT_) ? j : (TEXT_ + yrow*IMG_ + (j - TEXT_));
        const int cs = (lane & 7) ^ (lane >> 3);
        __builtin_amdgcn_global_load_lds((gu32*)(kpl + (size_t)krow*DH_ + cs*8),
            (lu32*)((char*)KVs + (p*32 + wave*8)*128), 16, 0, 0);
      }
    }
    __syncthreads();
    __builtin_amdgcn_s_setprio(1);
    #pragma unroll
    for (int kt2 = 0; kt2 < 8; ++kt2){
      if (kt2 < TC && (c*8 + kt2) <= ktlim){
        const int kt = c*8 + kt2;
        const int rr = kt2*16 + (lane & 15);
        bf16x8 b0 = *reinterpret_cast<const bf16x8*>((char*)KVs + rr*128 + (((0 + hi)*16) ^ ((rr&7)<<4)));
        bf16x8 b1 = *reinterpret_cast<const bf16x8*>((char*)KVs + rr*128 + (((4 + hi)*16) ^ ((rr&7)<<4)));
        sacc[kt] = __builtin_amdgcn_mfma_f32_16x16x32_bf16(qf[0], b0, sacc[kt], 0,0,0);
        sacc[kt] = __builtin_amdgcn_mfma_f32_16x16x32_bf16(qf[1], b1, sacc[kt], 0,0,0);
      }
    }
    __builtin_amdgcn_s_setprio(0);
  }

  // ---- causal mask (only tiles this wave computed) ----
  const int qb = wave*16 + hi*4;
  #pragma unroll
  for (int kt = 0; kt < NT; ++kt){
    if (kt <= ktlim && ((IMG && kt >= TEXT_/16) || (!IMG && kt*16 + 15 > Y*64))){
      #pragma unroll
      for (int reg = 0; reg < 4; ++reg){
        const int j = kt*16 + (lane & 15);
        const bool valid = IMG ? ((j - TEXT_) <= (qb + reg)) : (j <= Y*64 + qb + reg);
        if (!valid) sacc[kt][reg] = -1e30f;
      }
    }
  }

  // ---- exact softmax (exp2; skipped tiles stay 0 in sacc and excluded) ----
  float mr[4], inv[4];
  #pragma unroll
  for (int reg = 0; reg < 4; ++reg){
    float m = sacc[0][reg];
    #pragma unroll
    for (int kt = 1; kt < NT; ++kt) if (kt <= ktlim) m = fmaxf(m, sacc[kt][reg]);
    #pragma unroll
    for (int msk = 1; msk < 16; msk <<= 1) m = fmaxf(m, __shfl_xor(m, msk));
    mr[reg] = m;
  }
  #pragma unroll
  for (int reg = 0; reg < 4; ++reg){
    float l = 0.f;
    #pragma unroll
    for (int kt = 0; kt < NT; ++kt){
      if (kt <= ktlim){
        const float p = __builtin_amdgcn_exp2f(sacc[kt][reg] - mr[reg]);
        sacc[kt][reg] = p;
        l += p;
      }
    }
    #pragma unroll
    for (int msk = 1; msk < 16; msk <<= 1) l += __shfl_xor(l, msk);
    inv[reg] = 1.f / l;
  }

  // ---- PV (O^T via swapped operands) ----
  f32x4 oacc[4] = {};
  #pragma unroll
  for (int c = 0; c < NCH; ++c){
    const int TC = (NT - c*8 < 8) ? (NT - c*8) : 8;
    __syncthreads();
    if (TC == 8){
      // async V stage: 4 p-steps, rows dd = p*16 + wave*4 + hi (4 rows/instr),
      // src chunk = (lane&15) ^ (dd&7); all TC==8 chunks are text keys (j<256).
      #pragma unroll
      for (int p = 0; p < 4; ++p){
        const int dd = p*16 + wave*4 + (lane >> 4);
        const int ccs = (lane & 15) ^ (dd & 7);
        __builtin_amdgcn_global_load_lds((gu32*)(vTp + (size_t)dd*NTOK + c*128 + ccs*8),
            (lu32*)((char*)KVs + (p*16 + wave*4)*256), 16, 0, 0);
      }
    } else {
      // image / tail chunk: 64 keys per row, reg-staged (128B half-rows)
      #pragma unroll
      for (int p = 0; p < 2; ++p){
        const int idx = p*256 + tid;
        const int dd = idx >> 3;
        const int cc = idx & 7;
        const int j  = c*128 + cc*8;
        const int col = (!IMG || j < TEXT_) ? j : (TEXT_ + yrow*IMG_ + (j - TEXT_));
        u32x4 d = *reinterpret_cast<const u32x4*>(vTp + (size_t)dd*NTOK + col);
        *reinterpret_cast<u32x4*>((char*)KVs + dd*256 + ((cc*16) ^ ((dd&7)<<4))) = d;
      }
    }
    // write normalized P (bf16); skipped tiles have sacc==0 -> writes 0 (required:
    // Ps buffer is reused across chunks, so every slot must be refreshed)
    #pragma unroll
    for (int kt2 = 0; kt2 < 8; ++kt2){
      if (kt2 < TC){
        const int kt = c*8 + kt2;
        #pragma unroll
        for (int reg = 0; reg < 4; ++reg){
          const int q  = hi*4 + reg;
          const int kl = kt2*16 + (lane & 15);
          Ps[q*136 + kl] = f2bf(sacc[kt][reg] * inv[reg]);
        }
      }
    }
    __syncthreads();
    __builtin_amdgcn_s_setprio(1);
    #pragma unroll
    for (int kc = 0; kc < 4; ++kc){
      if (kc < TC/2 && (c*8 + kc*2) <= ktlim){
        bf16x8 pa = *reinterpret_cast<const bf16x8*>(&Ps[(lane & 15)*136 + kc*32 + hi*8]);
        #pragma unroll
        for (int ct = 0; ct < 4; ++ct){
          const int dd = ct*16 + (lane & 15);
          bf16x8 vb = *reinterpret_cast<const bf16x8*>((char*)KVs + dd*256 + (((kc*4 + hi)*16) ^ ((dd&7)<<4)));
          oacc[ct] = __builtin_amdgcn_mfma_f32_16x16x32_bf16(vb, pa, oacc[ct], 0,0,0);  // O^T
        }
      }
    }
    __builtin_amdgcn_s_setprio(0);
  }

  // ---- store O^T: lane owns q = lane&15; d = ct*16 + hi*4 + reg -> 8B stores ----
  const int b = bh >> 3, h = bh & 7;
  const int t = q0 + wave*16 + (lane & 15);
  u16* orow = att + ((size_t)b*NTOK + t)*DIM_ + h*DH_;
  #pragma unroll
  for (int ct = 0; ct < 4; ++ct){
    uint2 o;
    o.x = (unsigned)f2bf(oacc[ct][0]) | ((unsigned)f2bf(oacc[ct][1]) << 16);
    o.y = (unsigned)f2bf(oacc[ct][2]) | ((unsigned)f2bf(oacc[ct][3]) << 16);
    *reinterpret_cast<uint2*>(orow + ct*16 + hi*4) = o;
  }
}

// merged attention: y in [0,64) = image axial row y; y in [64,68) = text q-tile y-64
__global__ __launch_bounds__(256, 4) void k_attn(const u16* __restrict__ qkv, const u16* __restrict__ vT,
                                                 u16* __restrict__ att){
  __shared__ u16 KVs[128*64];
  __shared__ u16 Ps[4*16*136];
  const int y = blockIdx.y;
  if (y < 64){
    attn_core<20, true>(qkv, vT, att, KVs, Ps, blockIdx.x, y);
  } else {
    switch (y - 64){
      case 0: attn_core< 4, false>(qkv, vT, att, KVs, Ps, blockIdx.x, 0); break;
      case 1: attn_core< 8, false>(qkv, vT, att, KVs, Ps, blockIdx.x, 0); break;
      case 2: attn_core<12, false>(qkv, vT, att, KVs, Ps, blockIdx.x, 0); break;
      default: attn_core<16, false>(qkv, vT, att, KVs, Ps, blockIdx.x, 0); break;
    }
  }
}

// ---------------- launch ----------------
extern "C" void kernel_launch(void* const* d_in, const int* in_sizes, int n_in,
                              void* d_out, int out_size, void* d_ws, size_t ws_size,
                              hipStream_t stream) {
  const float* x     = (const float*)d_in[0];
  const float* w_qkv = (const float*)d_in[2];
  const float* w_out = (const float*)d_in[3];
  const float* b_out = (const float*)d_in[4];
  float* out = (float*)d_out;

  char* ws = (char*)d_ws;
  u16* xp  = (u16*)(ws);                                        // 17,825,792 B
  u16* vT  = (u16*)(ws + 17825792);                             // 17,825,792 B
  u16* wqT = (u16*)(ws + 2*17825792);                           //  1,572,864 B
  u16* woT = (u16*)(ws + 2*17825792 + 1572864);                 //    524,288 B
  u16* qk  = (u16*)(ws + 2*17825792 + 1572864 + 524288);        // 35,651,584 B (q,k planes)
  u16* att = (u16*)(ws + 2*17825792 + 1572864 + 524288 + 35651584); // 17,825,792 B

  k_prep     <<<dim3(12800),   dim3(256), 0, stream>>>(x, xp, w_qkv, wqT, w_out, woT);
  k_gemm_qkv <<<dim3(136, 12), dim3(256), 0, stream>>>(xp, wqT, qk, vT);
  k_attn     <<<dim3(32, 68),  dim3(256), 0, stream>>>(qk, vT, att);
  k_gemm_out <<<dim3(136, 4),  dim3(256), 0, stream>>>(att, woT, b_out, out);
}